// Round 7
// baseline (354.223 us; speedup 1.0000x reference)
//
#include <hip/hip_runtime.h>
#include <hip/hip_bf16.h>
#include <stdint.h>

// ---------------- problem dims ----------------
#define BTOT   65536
#define DIN    784
#define K1P    800     // layer-1 K padded: 784 data + bias row @784 + zeros
#define NH1    256
#define NH2    64
#define NEXP   10
#define BM     64
#define NKS1   25      // 800/32
#define NKS2   9       // 288/32 (256 + bias row @256 + zeros)

// ---------------- LDS layout (bytes) ----------------
#define XS_B      102400                   // 2 mb * 25 ks * 2 kh * 1024
#define H_OFF     XS_B
#define H_B       36864                    // 2 mb * 9 ks * 2 kh * 1024
#define EXP2_OFF  (H_OFF + H_B)            // 139264
#define W3S_OFF   (EXP2_OFF + BM * NEXP * 2 * 4)   // 144384
#define B3S_OFF   (W3S_OFF + NEXP * NH2 * 4)       // 146944
#define LDS_TOTAL (B3S_OFF + 64)           // 147008

typedef short s16x8  __attribute__((ext_vector_type(8)));
typedef float f32x4  __attribute__((ext_vector_type(4)));
typedef float f32x16 __attribute__((ext_vector_type(16)));

__device__ __forceinline__ short bf16b(float v) {
    __bf16 b = (__bf16)v;
    return __builtin_bit_cast(short, b);
}

// ---------------- prep: fragment-order weights (bf16, bias folded) ----------
__global__ void prep_w1(const float* __restrict__ W1, const float* __restrict__ b1,
                        const float* __restrict__ Wg1, const float* __restrict__ bg1,
                        __bf16* __restrict__ dst) {
    int t = blockIdx.x * 256 + threadIdx.x;          // < 11*8*25*2*64 = 281600
    int lane = t & 63;
    int rr = t >> 6;
    int kh = rr & 1;
    int ks = (rr >> 1) % 25;
    int nb = ((rr >> 1) / 25) % 8;
    int e  = (rr >> 1) / 200;
    int n  = nb * 32 + (lane & 31);
    int k0 = ks * 32 + kh * 16 + (lane >> 5) * 8;
    const float* src  = (e < NEXP) ? (W1 + (size_t)e * DIN * NH1) : Wg1;
    const float* bias = (e < NEXP) ? (b1 + e * NH1) : bg1;
    s16x8 o;
    #pragma unroll
    for (int j = 0; j < 8; ++j) {
        int k = k0 + j;
        float v = (k < DIN) ? src[(size_t)k * NH1 + n]
                            : ((k == DIN) ? bias[n] : 0.f);
        o[j] = bf16b(v);
    }
    *(s16x8*)((short*)dst + (size_t)t * 8) = o;
}

__global__ void prep_w2(const float* __restrict__ W2, const float* __restrict__ b2,
                        __bf16* __restrict__ dst) {
    int t = blockIdx.x * 256 + threadIdx.x;          // < 10*2*9*2*64 = 23040
    int lane = t & 63;
    int rr = t >> 6;
    int kh = rr & 1;
    int ks = (rr >> 1) % 9;
    int jb = ((rr >> 1) / 9) & 1;
    int e  = (rr >> 1) / 18;
    int n  = jb * 32 + (lane & 31);
    int k0 = ks * 32 + kh * 16 + (lane >> 5) * 8;
    s16x8 o;
    #pragma unroll
    for (int j = 0; j < 8; ++j) {
        int k = k0 + j;
        float v = (k < NH1) ? W2[((size_t)e * NH1 + k) * NH2 + n]
                            : ((k == NH1) ? b2[e * NH2 + n] : 0.f);
        o[j] = bf16b(v);
    }
    *(s16x8*)((short*)dst + (size_t)t * 8) = o;
}

__global__ void prep_wg2(const float* __restrict__ Wg2, const float* __restrict__ bg2,
                         __bf16* __restrict__ dst) {
    int t = blockIdx.x * 256 + threadIdx.x;
    if (t >= 9 * 2 * 64) return;
    int lane = t & 63;
    int rr = t >> 6;
    int kh = rr & 1;
    int ks = rr >> 1;
    int n  = lane & 31;
    int k0 = ks * 32 + kh * 16 + (lane >> 5) * 8;
    s16x8 o;
    #pragma unroll
    for (int j = 0; j < 8; ++j) {
        int k = k0 + j;
        float v = 0.f;
        if (n < NEXP) {
            if (k < NH1)       v = Wg2[(size_t)k * NEXP + n];
            else if (k == NH1) v = bg2[n];
        }
        o[j] = bf16b(v);
    }
    *(s16x8*)((short*)dst + (size_t)t * 8) = o;
}

// ---- macro bodies (slot/expert indices literal -> arrays stay in registers) ----
#define PFA(S, T)                                                             \
    { _Pragma("unroll") for (int mt = 0; mt < 2; ++mt)                        \
        _Pragma("unroll") for (int kh = 0; kh < 2; ++kh)                      \
            a[S][mt][kh] = *(const s16x8*)(pA + ((mt * 25 + (T)) * 2 + kh) * 1024); }

#define PFW(S, E, T, PW)                                                      \
    { _Pragma("unroll") for (int nt = 0; nt < 2; ++nt)                        \
        _Pragma("unroll") for (int kh = 0; kh < 2; ++kh)                      \
            w[S][E][nt][kh] = *(const s16x8*)((PW) + nt * 51200                \
                                              + ((T) * 2 + kh) * 1024); }

#define PMMA(S, E)                                                            \
    { _Pragma("unroll") for (int nt = 0; nt < 2; ++nt)                        \
        _Pragma("unroll") for (int mt = 0; mt < 2; ++mt)                      \
            _Pragma("unroll") for (int kh = 0; kh < 2; ++kh)                  \
                acc[E][nt][mt] = __builtin_amdgcn_mfma_f32_32x32x16_bf16(     \
                    w[S][E][nt][kh], a[S][mt][kh], acc[E][nt][mt], 0, 0, 0); }

#define ZACC(E)                                                               \
    { _Pragma("unroll") for (int nt = 0; nt < 2; ++nt)                        \
        _Pragma("unroll") for (int mt = 0; mt < 2; ++mt)                      \
            _Pragma("unroll") for (int q = 0; q < 16; ++q)                    \
                acc[E][nt][mt][q] = 0.f; }

// h[m][n] = relu(acc[E]); fragment layout write (b64, 2-way max)
#define HWRITE(E)                                                             \
    { _Pragma("unroll") for (int mt = 0; mt < 2; ++mt)                        \
        _Pragma("unroll") for (int nt = 0; nt < 2; ++nt) {                    \
            const int ks2 = wave * 2 + nt;                                    \
            _Pragma("unroll") for (int q = 0; q < 4; ++q) {                   \
                uint2 wv; short* p = (short*)&wv;                             \
                _Pragma("unroll") for (int r2 = 0; r2 < 4; ++r2)              \
                    p[r2] = bf16b(fmaxf(acc[E][nt][mt][q * 4 + r2], 0.f));    \
                *(uint2*)(hb + ((mt * 9 + ks2) * 2 + (q >> 1)) * 1024         \
                             + (q & 1) * 512 + rl * 16 + hi * 8) = wv;        \
            } } }

#define PF_V2(PV)                                                             \
    { _Pragma("unroll") for (int p = 0; p < 3; ++p)                           \
        _Pragma("unroll") for (int kh = 0; kh < 2; ++kh)                      \
            v2[p][kh] = *(const s16x8*)((PV) + (p * 2 + kh) * 1024); }

#define L2_PF(S, T)                                                           \
    { _Pragma("unroll") for (int kh = 0; kh < 2; ++kh) {                      \
        hfr[S][kh] = *(const s16x8*)(pH + ((T) * 2 + kh) * 1024);             \
        v2[S][kh]  = *(const s16x8*)(pV + ((T) * 2 + kh) * 1024); } }

#define L2_MMA(S)                                                             \
    { _Pragma("unroll") for (int kh = 0; kh < 2; ++kh)                        \
        acc2 = __builtin_amdgcn_mfma_f32_32x32x16_bf16(                       \
            v2[S][kh], hfr[S][kh], acc2, 0, 0, 0); }

// layer-2 (9 steps, depth-3; v2 slots preloaded) + layer-3 partial (no b3)
#define DO_L2(EV, PV)                                                         \
    {                                                                         \
        const char* pV = (PV);                                                \
        f32x16 acc2;                                                          \
        _Pragma("unroll") for (int q = 0; q < 16; ++q) acc2[q] = 0.f;         \
        _Pragma("unroll") for (int kh = 0; kh < 2; ++kh)                      \
            hfr[0][kh] = *(const s16x8*)(pH + (0 * 2 + kh) * 1024);           \
        _Pragma("unroll") for (int kh = 0; kh < 2; ++kh)                      \
            hfr[1][kh] = *(const s16x8*)(pH + (1 * 2 + kh) * 1024);           \
        _Pragma("unroll") for (int kh = 0; kh < 2; ++kh)                      \
            hfr[2][kh] = *(const s16x8*)(pH + (2 * 2 + kh) * 1024);           \
        _Pragma("unroll 1") for (int T = 0; T < 2; ++T) {                     \
            const int t3 = 3 * T;                                             \
            L2_MMA(0) L2_PF(0, t3 + 3)                                        \
            L2_MMA(1) L2_PF(1, t3 + 4)                                        \
            L2_MMA(2) L2_PF(2, t3 + 5)                                        \
        }                                                                     \
        L2_MMA(0) L2_MMA(1) L2_MMA(2)                                         \
        float part = 0.f;                                                     \
        const float* w3p = w3s + (EV) * NH2 + jb * 32 + 4 * hi;               \
        _Pragma("unroll") for (int q = 0; q < 4; ++q) {                       \
            f32x4 w3v = *(const f32x4*)(w3p + 8 * q);                         \
            _Pragma("unroll") for (int r2 = 0; r2 < 4; ++r2)                  \
                part += fmaxf(acc2[q * 4 + r2], 0.f) * w3v[r2];               \
        }                                                                     \
        part += __shfl_xor(part, 32, 64);                                     \
        if (hi == 0)                                                          \
            expl2[(mb2 * 32 + rl) * (NEXP * 2) + (EV) * 2 + jb] = part;       \
    }

// ---------------- fused MoE kernel ----------------
// 4 waves, 64 rows/block, 1 wave/SIMD by design (147KB LDS). ILP doubled by
// processing experts in PAIRS: one K-sweep computes layer-1 for e and e+1
// (16 MFMA per 8 weight loads + 4 shared x ds_reads; dep distance 2 steps).
// ~270 VGPR, fine at 1 wave/SIMD (512 budget).
__global__ void __launch_bounds__(256, 1)
moe_fused(const float* __restrict__ x, const float* __restrict__ W3,
          const float* __restrict__ b3, const __bf16* __restrict__ w1t,
          const __bf16* __restrict__ w2t, const __bf16* __restrict__ wg2t,
          float* __restrict__ out)
{
    extern __shared__ char lds[];
    char*  xsb   = lds;
    char*  hb    = lds + H_OFF;
    float* expl2 = (float*)(lds + EXP2_OFF);   // [64 m][10 e][2 jb]
    float* w3s   = (float*)(lds + W3S_OFF);
    float* b3s   = (float*)(lds + B3S_OFF);

    const int tid  = threadIdx.x;
    const int lane = tid & 63;
    const int wave = tid >> 6;
    const int rl   = lane & 31;
    const int hi   = lane >> 5;
    const int row0 = blockIdx.x * BM;
    const char* w1c = (const char*)w1t;

    const char* pA = xsb + lane * 16;
    const int mb2 = wave >> 1, jb = wave & 1;
    const char* pH = hb + mb2 * 18432 + lane * 16;

    // ---- issue pair-0 weight slots FIRST (hide under x staging) ----
    s16x8 w[2][2][2][2];        // [slot][expert][nt][kh]
    s16x8 a[2][2][2];           // [slot][mt][kh]
    s16x8 v2[3][2], hfr[3][2];
    {
        const char* pW0 = w1c + (size_t)(wave * 2) * 51200 + lane * 16;
        const char* pW1 = pW0 + 8 * 51200;
        PFW(0, 0, 0, pW0) PFW(1, 0, 1, pW0)
        PFW(0, 1, 0, pW1) PFW(1, 1, 1, pW1)
    }

    // ---- stage x tile fp32 -> bf16 fragment layout ----
    {
        const float* xg = x + (size_t)row0 * DIN;
        #pragma unroll 4
        for (int i = 0; i < 49; ++i) {               // 49*256 == 64*196
            int idx = tid + i * 256;
            int r = idx / 196, c = (idx % 196) * 4;
            float4 v = *(const float4*)(xg + (size_t)r * DIN + c);
            int ks = c >> 5, kin = c & 31;
            int kh = kin >> 4, hw = (kin >> 3) & 1, j = c & 7;
            uint2 wv; short* p = (short*)&wv;
            p[0] = bf16b(v.x); p[1] = bf16b(v.y);
            p[2] = bf16b(v.z); p[3] = bf16b(v.w);
            *(uint2*)(xsb + ((((r >> 5) * 25 + ks) * 2 + kh) * 2 + hw) * 512
                          + (r & 31) * 16 + j * 2) = wv;
        }
        for (int i = tid; i < 64 * 4; i += 256) {    // k=784 bias-1 .. 799 zeros
            int r = i >> 2, g = i & 3;
            int hw = g >> 1, j0 = (g & 1) * 4;
            uint2 wv = {0u, 0u};
            if (g == 0) ((short*)&wv)[0] = bf16b(1.f);
            *(uint2*)(xsb + ((((r >> 5) * 25 + 24) * 2 + 1) * 2 + hw) * 512
                          + (r & 31) * 16 + j0 * 2) = wv;
        }
        for (int i = tid; i < 2 * 1024; i += 256) {  // h pad block ks2=8
            int mb = i >> 10, q = i & 1023;
            short v = (q < 256 && (q & 7) == 0) ? bf16b(1.f) : (short)0;
            *(short*)(hb + (mb * 9 + 8) * 2048 + q * 2) = v;
        }
        for (int i = tid; i < NEXP * NH2; i += 256) w3s[i] = W3[i];
        if (tid < NEXP) b3s[tid] = b3[tid];
    }
    __syncthreads();

    // a-slot prologue for pair 0
    PFA(0, 0) PFA(1, 1)

    f32x16 acc[2][2][2];        // [expert][nt][mt]

    #pragma unroll 1
    for (int p5 = 0; p5 < 5; ++p5) {
        const int e0 = 2 * p5;
        const char* pW0 = w1c + (size_t)(e0 * 8 + wave * 2) * 51200 + lane * 16;
        const char* pW1 = pW0 + 8 * 51200;

        ZACC(0) ZACC(1)

        // ---- paired K loop: 2 slots, dep distance 2 steps (~1000+ cyc) ----
        #pragma unroll 1
        for (int T = 0; T < 11; ++T) {               // t = 2T, 2T+1: 0..21
            const int t2 = 2 * T;
            PMMA(0, 0) PMMA(0, 1)
            PFW(0, 0, t2 + 2, pW0) PFW(0, 1, t2 + 2, pW1) PFA(0, t2 + 2)
            PMMA(1, 0) PMMA(1, 1)
            PFW(1, 0, t2 + 3, pW0) PFW(1, 1, t2 + 3, pW1) PFA(1, t2 + 3)
        }
        PMMA(0, 0) PMMA(0, 1)                        // t=22
        PFW(0, 0, 24, pW0) PFW(0, 1, 24, pW1) PFA(0, 24)
        PMMA(1, 0) PMMA(1, 1)                        // t=23
        PMMA(0, 0) PMMA(0, 1)                        // t=24

        // prefetch: L2 v-slots for e0, then next pair (or gate) L1 slots —
        // latency hides under barriers + epilogues
        PF_V2((const char*)w2t + (size_t)(e0 * 2 + jb) * 18432 + lane * 16)
        {
            const char* pW0n = pW0 + 16 * 51200;             // e0+2 (p5==4 -> gate)
            const char* pW1n = (p5 < 4) ? (pW1 + 16 * 51200) : pW0n;
            PFW(0, 0, 0, pW0n) PFW(1, 0, 1, pW0n)
            PFW(0, 1, 0, pW1n) PFW(1, 1, 1, pW1n)
            PFA(0, 0) PFA(1, 1)
        }

        __syncthreads();   // (1) prev h readers done
        HWRITE(0)
        __syncthreads();   // (2) h(e0) ready
        DO_L2(e0, (const char*)w2t + (size_t)(e0 * 2 + jb) * 18432 + lane * 16)
        PF_V2((const char*)w2t + (size_t)((e0 + 1) * 2 + jb) * 18432 + lane * 16)
        __syncthreads();   // (3) h(e0) readers done
        HWRITE(1)
        __syncthreads();   // (4) h(e1) ready
        DO_L2(e0 + 1, (const char*)w2t + (size_t)((e0 + 1) * 2 + jb) * 18432 + lane * 16)
    }

    // ================= gate: layer-1 (expert 10), single pipeline =========
    {
        const char* pWg = w1c + (size_t)(10 * 8 + wave * 2) * 51200 + lane * 16;
        ZACC(0)
        #pragma unroll 1
        for (int T = 0; T < 11; ++T) {               // t = 2T, 2T+1: 0..21
            const int t2 = 2 * T;
            PMMA(0, 0) PFW(0, 0, t2 + 2, pWg) PFA(0, t2 + 2)
            PMMA(1, 0) PFW(1, 0, t2 + 3, pWg) PFA(1, t2 + 3)
        }
        PMMA(0, 0) PFW(0, 0, 24, pWg) PFA(0, 24)     // t=22
        PMMA(1, 0)                                   // t=23
        PMMA(0, 0)                                   // t=24

        __syncthreads();   // h(e9) readers done
        HWRITE(0)
        __syncthreads();   // g ready
    }

    // ================= gate logits -> softmax -> combine ==================
    if (wave < 2) {
        const int mbg = wave;
        const char* pHg = hb + mbg * 18432 + lane * 16;
        const char* pG  = (const char*)wg2t + lane * 16;
        f32x16 acc3;
        #pragma unroll
        for (int q = 0; q < 16; ++q) acc3[q] = 0.f;
        {
            const char* pH = pHg;
            const char* pV = pG;
            L2_PF(0, 0) L2_PF(1, 1) L2_PF(2, 2)
            #define acc2 acc3
            #pragma unroll 1
            for (int T = 0; T < 2; ++T) {
                const int t3 = 3 * T;
                L2_MMA(0) L2_PF(0, t3 + 3)
                L2_MMA(1) L2_PF(1, t3 + 4)
                L2_MMA(2) L2_PF(2, t3 + 5)
            }
            L2_MMA(0) L2_MMA(1) L2_MMA(2)
            #undef acc2
        }
        // lane m = mbg*32+rl; reg q*4+r2 -> j = r2+8q+4hi (valid <10)
        const int m = mbg * 32 + rl;
        float mx = -1e30f;
        float lv[16];
        #pragma unroll
        for (int q = 0; q < 4; ++q)
            #pragma unroll
            for (int r2 = 0; r2 < 4; ++r2) {
                int j = r2 + 8 * q + 4 * hi;
                int rg = q * 4 + r2;
                lv[rg] = (j < NEXP) ? acc3[rg] : -1e30f;
                mx = fmaxf(mx, lv[rg]);
            }
        mx = fmaxf(mx, __shfl_xor(mx, 32, 64));
        float s = 0.f;
        float pv[16];
        #pragma unroll
        for (int rg = 0; rg < 16; ++rg) {
            pv[rg] = (lv[rg] > -1e29f) ? __expf(lv[rg] - mx) : 0.f;
            s += pv[rg];
        }
        s += __shfl_xor(s, 32, 64);
        const float inv = 1.f / s;
        #pragma unroll
        for (int q = 0; q < 4; ++q)
            #pragma unroll
            for (int r2 = 0; r2 < 4; ++r2) {
                int j = r2 + 8 * q + 4 * hi;
                if (j < NEXP) {
                    float g  = pv[q * 4 + r2] * inv;
                    float eo = expl2[m * (NEXP * 2) + j * 2]
                             + expl2[m * (NEXP * 2) + j * 2 + 1]
                             + b3s[j];
                    size_t o = (size_t)(row0 + m) * NEXP + j;
                    out[o] = g * eo;
                    out[(size_t)BTOT * NEXP + o] = g;
                    out[(size_t)2 * BTOT * NEXP + o] = eo;
                }
            }
    }
}

extern "C" void kernel_launch(void* const* d_in, const int* in_sizes, int n_in,
                              void* d_out, int out_size, void* d_ws, size_t ws_size,
                              hipStream_t stream) {
    (void)in_sizes; (void)n_in; (void)out_size; (void)ws_size;
    const float* x   = (const float*)d_in[0];
    const float* W1  = (const float*)d_in[1];
    const float* b1  = (const float*)d_in[2];
    const float* W2  = (const float*)d_in[3];
    const float* b2  = (const float*)d_in[4];
    const float* W3  = (const float*)d_in[5];
    const float* b3  = (const float*)d_in[6];
    const float* Wg1 = (const float*)d_in[7];
    const float* bg1 = (const float*)d_in[8];
    const float* Wg2 = (const float*)d_in[9];
    const float* bg2 = (const float*)d_in[10];

    // ws (bf16, fragment order): w1t 11*8*25*2*64*8 | w2t 10*2*9*2*64*8 | wg2t 9*2*64*8
    __bf16* w1t  = (__bf16*)d_ws;
    __bf16* w2t  = w1t + (size_t)11 * 8 * 25 * 2 * 64 * 8;
    __bf16* wg2t = w2t + (size_t)10 * 2 * 9 * 2 * 64 * 8;

    hipFuncSetAttribute((const void*)moe_fused,
                        hipFuncAttributeMaxDynamicSharedMemorySize, LDS_TOTAL);

    prep_w1<<<1100, 256, 0, stream>>>(W1, b1, Wg1, bg1, w1t);
    prep_w2<<<90, 256, 0, stream>>>(W2, b2, w2t);
    prep_wg2<<<5, 256, 0, stream>>>(Wg2, bg2, wg2t);
    moe_fused<<<BTOT / BM, 256, LDS_TOTAL, stream>>>(x, W3, b3, w1t, w2t, wg2t,
                                                     (float*)d_out);
}

// Round 8
// 349.484 us; speedup vs baseline: 1.0136x; 1.0136x over previous
//
#include <hip/hip_runtime.h>
#include <hip/hip_bf16.h>
#include <stdint.h>

// ---------------- problem dims ----------------
#define BTOT   65536
#define DIN    784
#define K1P    800     // layer-1 K padded: 784 data + bias row @784 + zeros
#define NH1    256
#define NH2    64
#define NEXP   10
#define BM     64
#define NKS1   25      // 800/32
#define NKS2   9       // 288/32 (256 + bias row @256 + zeros)

// ---------------- LDS layout (bytes) ----------------
#define XS_B      102400                   // 2 mb * 25 ks * 2 kh * 1024
#define H_OFF     XS_B
#define H_B       36864                    // 2 mb * 9 ks * 2 kh * 1024
#define EXP2_OFF  (H_OFF + H_B)            // 139264
#define W3S_OFF   (EXP2_OFF + BM * NEXP * 2 * 4)   // 144384
#define B3S_OFF   (W3S_OFF + NEXP * NH2 * 4)       // 146944
#define LDS_TOTAL (B3S_OFF + 64)           // 147008

typedef short s16x8  __attribute__((ext_vector_type(8)));
typedef float f32x4  __attribute__((ext_vector_type(4)));
typedef float f32x16 __attribute__((ext_vector_type(16)));

#define SB() __builtin_amdgcn_sched_barrier(0)

__device__ __forceinline__ short bf16b(float v) {
    __bf16 b = (__bf16)v;
    return __builtin_bit_cast(short, b);
}

// ---------------- prep: fragment-order weights (bf16, bias folded) ----------
__global__ void prep_w1(const float* __restrict__ W1, const float* __restrict__ b1,
                        const float* __restrict__ Wg1, const float* __restrict__ bg1,
                        __bf16* __restrict__ dst) {
    int t = blockIdx.x * 256 + threadIdx.x;          // < 11*8*25*2*64 = 281600
    int lane = t & 63;
    int rr = t >> 6;
    int kh = rr & 1;
    int ks = (rr >> 1) % 25;
    int nb = ((rr >> 1) / 25) % 8;
    int e  = (rr >> 1) / 200;
    int n  = nb * 32 + (lane & 31);
    int k0 = ks * 32 + kh * 16 + (lane >> 5) * 8;
    const float* src  = (e < NEXP) ? (W1 + (size_t)e * DIN * NH1) : Wg1;
    const float* bias = (e < NEXP) ? (b1 + e * NH1) : bg1;
    s16x8 o;
    #pragma unroll
    for (int j = 0; j < 8; ++j) {
        int k = k0 + j;
        float v = (k < DIN) ? src[(size_t)k * NH1 + n]
                            : ((k == DIN) ? bias[n] : 0.f);
        o[j] = bf16b(v);
    }
    *(s16x8*)((short*)dst + (size_t)t * 8) = o;
}

__global__ void prep_w2(const float* __restrict__ W2, const float* __restrict__ b2,
                        __bf16* __restrict__ dst) {
    int t = blockIdx.x * 256 + threadIdx.x;          // < 10*2*9*2*64 = 23040
    int lane = t & 63;
    int rr = t >> 6;
    int kh = rr & 1;
    int ks = (rr >> 1) % 9;
    int jb = ((rr >> 1) / 9) & 1;
    int e  = (rr >> 1) / 18;
    int n  = jb * 32 + (lane & 31);
    int k0 = ks * 32 + kh * 16 + (lane >> 5) * 8;
    s16x8 o;
    #pragma unroll
    for (int j = 0; j < 8; ++j) {
        int k = k0 + j;
        float v = (k < NH1) ? W2[((size_t)e * NH1 + k) * NH2 + n]
                            : ((k == NH1) ? b2[e * NH2 + n] : 0.f);
        o[j] = bf16b(v);
    }
    *(s16x8*)((short*)dst + (size_t)t * 8) = o;
}

__global__ void prep_wg2(const float* __restrict__ Wg2, const float* __restrict__ bg2,
                         __bf16* __restrict__ dst) {
    int t = blockIdx.x * 256 + threadIdx.x;
    if (t >= 9 * 2 * 64) return;
    int lane = t & 63;
    int rr = t >> 6;
    int kh = rr & 1;
    int ks = rr >> 1;
    int n  = lane & 31;
    int k0 = ks * 32 + kh * 16 + (lane >> 5) * 8;
    s16x8 o;
    #pragma unroll
    for (int j = 0; j < 8; ++j) {
        int k = k0 + j;
        float v = 0.f;
        if (n < NEXP) {
            if (k < NH1)       v = Wg2[(size_t)k * NEXP + n];
            else if (k == NH1) v = bg2[n];
        }
        o[j] = bf16b(v);
    }
    *(s16x8*)((short*)dst + (size_t)t * 8) = o;
}

// ---- macro bodies (slot index literal -> arrays stay in registers) ----
#define L1A_PF(S, T)                                                          \
    { _Pragma("unroll") for (int mt = 0; mt < 2; ++mt)                        \
        _Pragma("unroll") for (int kh = 0; kh < 2; ++kh)                      \
            a[S][mt][kh] = *(const s16x8*)(pA + ((mt * 25 + (T)) * 2 + kh) * 1024); }

#define L1W_PF(S, T, PW)                                                      \
    { _Pragma("unroll") for (int nt = 0; nt < 2; ++nt)                        \
        _Pragma("unroll") for (int kh = 0; kh < 2; ++kh)                      \
            w[S][nt][kh] = *(const s16x8*)((PW) + nt * 51200 + ((T) * 2 + kh) * 1024); }

#define L1_PF(S, T) L1A_PF(S, T) L1W_PF(S, T, pW)

// kh OUTERMOST: no adjacent same-acc MFMAs (dep distance = 4 MFMAs)
#define L1_MMA(S)                                                             \
    { _Pragma("unroll") for (int kh = 0; kh < 2; ++kh)                        \
        _Pragma("unroll") for (int nt = 0; nt < 2; ++nt)                      \
            _Pragma("unroll") for (int mt = 0; mt < 2; ++mt)                  \
                acc[nt][mt] = __builtin_amdgcn_mfma_f32_32x32x16_bf16(        \
                    w[S][nt][kh], a[S][mt][kh], acc[nt][mt], 0, 0, 0); }

#define L2_PF(S, T)                                                           \
    { _Pragma("unroll") for (int kh = 0; kh < 2; ++kh) {                      \
        hfr[S][kh] = *(const s16x8*)(pH + ((T) * 2 + kh) * 1024);             \
        v2[S][kh]  = *(const s16x8*)(pV + ((T) * 2 + kh) * 1024); } }

// split accumulators (one per kh): halves the single-chain RAW dependency
#define L2_MMA(S)                                                             \
    { acc2a = __builtin_amdgcn_mfma_f32_32x32x16_bf16(v2[S][0], hfr[S][0],    \
                                                      acc2a, 0, 0, 0);        \
      acc2b = __builtin_amdgcn_mfma_f32_32x32x16_bf16(v2[S][1], hfr[S][1],    \
                                                      acc2b, 0, 0, 0); }

// ---------------- fused MoE kernel ----------------
// 4 waves, 64 rows/block, 1 wave/SIMD (147KB LDS). Weights stream
// global->reg through 3-deep rotating slots; sched_barrier(0) fences pin
// the {MMA -> prefetch} phase order so the compiler cannot sink the loads
// to their uses (the r4-r7 ~35% plateau mechanism).
__global__ void __launch_bounds__(256, 1)
moe_fused(const float* __restrict__ x, const float* __restrict__ W3,
          const float* __restrict__ b3, const __bf16* __restrict__ w1t,
          const __bf16* __restrict__ w2t, const __bf16* __restrict__ wg2t,
          float* __restrict__ out)
{
    extern __shared__ char lds[];
    char*  xsb   = lds;
    char*  hb    = lds + H_OFF;
    float* expl2 = (float*)(lds + EXP2_OFF);   // [64 m][10 e][2 jb]
    float* w3s   = (float*)(lds + W3S_OFF);
    float* b3s   = (float*)(lds + B3S_OFF);

    const int tid  = threadIdx.x;
    const int lane = tid & 63;
    const int wave = tid >> 6;
    const int rl   = lane & 31;
    const int hi   = lane >> 5;
    const int row0 = blockIdx.x * BM;
    const char* w1c = (const char*)w1t;

    const char* pA = xsb + lane * 16;

    // ---- issue expert-0 weight slots FIRST (hide under x staging) ----
    s16x8 w[3][2][2], a[3][2][2];
    {
        const char* pW = w1c + (size_t)(wave * 2) * 51200 + lane * 16;
        L1W_PF(0, 0, pW) L1W_PF(1, 1, pW) L1W_PF(2, 2, pW)
    }

    // ---- stage x tile fp32 -> bf16 fragment layout ----
    {
        const float* xg = x + (size_t)row0 * DIN;
        #pragma unroll 4
        for (int i = 0; i < 49; ++i) {               // 49*256 == 64*196
            int idx = tid + i * 256;
            int r = idx / 196, c = (idx % 196) * 4;
            float4 v = *(const float4*)(xg + (size_t)r * DIN + c);
            int ks = c >> 5, kin = c & 31;
            int kh = kin >> 4, hw = (kin >> 3) & 1, j = c & 7;
            uint2 wv; short* p = (short*)&wv;
            p[0] = bf16b(v.x); p[1] = bf16b(v.y);
            p[2] = bf16b(v.z); p[3] = bf16b(v.w);
            *(uint2*)(xsb + ((((r >> 5) * 25 + ks) * 2 + kh) * 2 + hw) * 512
                          + (r & 31) * 16 + j * 2) = wv;
        }
        for (int i = tid; i < 64 * 4; i += 256) {    // k=784 bias-1 .. 799 zeros
            int r = i >> 2, g = i & 3;
            int hw = g >> 1, j0 = (g & 1) * 4;
            uint2 wv = {0u, 0u};
            if (g == 0) ((short*)&wv)[0] = bf16b(1.f);
            *(uint2*)(xsb + ((((r >> 5) * 25 + 24) * 2 + 1) * 2 + hw) * 512
                          + (r & 31) * 16 + j0 * 2) = wv;
        }
        for (int i = tid; i < 2 * 1024; i += 256) {  // h pad block ks2=8
            int mb = i >> 10, q = i & 1023;
            short v = (q < 256 && (q & 7) == 0) ? bf16b(1.f) : (short)0;
            *(short*)(hb + (mb * 9 + 8) * 2048 + q * 2) = v;
        }
        for (int i = tid; i < NEXP * NH2; i += 256) w3s[i] = W3[i];
        if (tid < NEXP) b3s[tid] = b3[tid];
    }
    __syncthreads();

    // a-slot prologue for expert 0
    L1A_PF(0, 0) L1A_PF(1, 1) L1A_PF(2, 2)

    #pragma unroll 1
    for (int e = 0; e <= NEXP; ++e) {
        const char* pWe = w1c + (size_t)(e * 8 + wave * 2) * 51200 + lane * 16;
        #define pW pWe

        f32x16 acc[2][2];
        #pragma unroll
        for (int nt = 0; nt < 2; ++nt)
            #pragma unroll
            for (int mt = 0; mt < 2; ++mt)
                #pragma unroll
                for (int q = 0; q < 16; ++q) acc[nt][mt][q] = 0.f;

        // ---- K loop: rolled, 3 slot-bodies/iter; SB() pins phase order ----
        #pragma unroll 1
        for (int T = 0; T < 7; ++T) {                // t = 3T+s, covers 0..20
            const int t3 = 3 * T;
            L1_MMA(0) SB(); L1_PF(0, t3 + 3) SB();
            L1_MMA(1) SB(); L1_PF(1, t3 + 4) SB();
            L1_MMA(2) SB(); L1_PF(2, t3 + 5) SB();
        }
        L1_MMA(0) SB(); L1_PF(0, 24) SB();           // t=21
        L1_MMA(1) SB();                              // t=22
        L1_MMA(2) SB();                              // t=23
        #undef pW

        // layer-2 weight slots (early: latency hides under epilogue)
        const int mb2 = wave >> 1, jb = wave & 1;
        const char* pH = hb + mb2 * 18432 + lane * 16;
        const char* pV = (const char*)w2t + (size_t)(e * 2 + jb) * 18432 + lane * 16;
        s16x8 v2[3][2], hfr[3][2];
        if (e < NEXP) {
            #pragma unroll
            for (int p = 0; p < 3; ++p)
                #pragma unroll
                for (int kh = 0; kh < 2; ++kh)
                    v2[p][kh] = *(const s16x8*)(pV + (p * 2 + kh) * 1024);
        }
        SB();
        L1_MMA(0)                                    // t=24

        // refill slots for expert e+1 (w from global, a from LDS)
        if (e < NEXP) {
            const char* pWn = pWe + 8 * 51200;
            L1W_PF(0, 0, pWn) L1W_PF(1, 1, pWn) L1W_PF(2, 2, pWn)
            L1A_PF(0, 0) L1A_PF(1, 1) L1A_PF(2, 2)
        }

        __syncthreads();   // (1) all waves done reading previous h
        // h-write in fragment layout: lane m = mt*32+rl; reg q*4+r2 ->
        // n_local = r2 + 8q + 4hi -> (kh2=q>>1, hi2=q&1, j=r2+4hi)
        #pragma unroll
        for (int mt = 0; mt < 2; ++mt)
            #pragma unroll
            for (int nt = 0; nt < 2; ++nt) {
                const int ks2 = wave * 2 + nt;
                #pragma unroll
                for (int q = 0; q < 4; ++q) {
                    uint2 wv; short* p = (short*)&wv;
                    #pragma unroll
                    for (int r2 = 0; r2 < 4; ++r2)
                        p[r2] = bf16b(fmaxf(acc[nt][mt][q * 4 + r2], 0.f));
                    *(uint2*)(hb + ((mt * 9 + ks2) * 2 + (q >> 1)) * 1024
                                 + (q & 1) * 512 + rl * 16 + hi * 8) = wv;
                }
            }
        __syncthreads();   // (2) h ready

        if (e < NEXP) {
            // ================= layer 2: 9 steps, depth-3 slots =============
            f32x16 acc2a, acc2b;
            #pragma unroll
            for (int q = 0; q < 16; ++q) { acc2a[q] = 0.f; acc2b[q] = 0.f; }
            #pragma unroll
            for (int kh = 0; kh < 2; ++kh)
                hfr[0][kh] = *(const s16x8*)(pH + (0 * 2 + kh) * 1024);
            #pragma unroll
            for (int kh = 0; kh < 2; ++kh)
                hfr[1][kh] = *(const s16x8*)(pH + (1 * 2 + kh) * 1024);
            #pragma unroll
            for (int kh = 0; kh < 2; ++kh)
                hfr[2][kh] = *(const s16x8*)(pH + (2 * 2 + kh) * 1024);

            #pragma unroll 1
            for (int T = 0; T < 2; ++T) {            // t = 3T+s, covers 0..5
                const int t3 = 3 * T;
                L2_MMA(0) SB(); L2_PF(0, t3 + 3) SB();
                L2_MMA(1) SB(); L2_PF(1, t3 + 4) SB();
                L2_MMA(2) SB(); L2_PF(2, t3 + 5) SB();
            }
            L2_MMA(0) L2_MMA(1) L2_MMA(2)            // t = 6,7,8

            // ---- layer 3: lane m = mb2*32+rl; j = jb*32 + r2+8q+4hi ----
            // b3 added ONCE at the gate-combine.
            float part = 0.f;
            const float* w3p = w3s + e * NH2 + jb * 32 + 4 * hi;
            #pragma unroll
            for (int q = 0; q < 4; ++q) {
                f32x4 w3v = *(const f32x4*)(w3p + 8 * q);
                #pragma unroll
                for (int r2 = 0; r2 < 4; ++r2)
                    part += fmaxf(acc2a[q * 4 + r2] + acc2b[q * 4 + r2], 0.f) * w3v[r2];
            }
            part += __shfl_xor(part, 32, 64);
            if (hi == 0)
                expl2[(mb2 * 32 + rl) * (NEXP * 2) + e * 2 + jb] = part;
        } else if (wave < 2) {
            // ================= gate: logits -> softmax -> combine ==========
            const int mbg = wave;
            const char* pHg = hb + mbg * 18432 + lane * 16;
            const char* pG  = (const char*)wg2t + lane * 16;
            f32x16 acc3a, acc3b;
            #pragma unroll
            for (int q = 0; q < 16; ++q) { acc3a[q] = 0.f; acc3b[q] = 0.f; }
            {
                s16x8 v2[3][2], hfr[3][2];
                const char* pH = pHg;
                const char* pV = pG;
                L2_PF(0, 0) L2_PF(1, 1) L2_PF(2, 2)
                #define acc2a acc3a
                #define acc2b acc3b
                #pragma unroll 1
                for (int T = 0; T < 2; ++T) {
                    const int t3 = 3 * T;
                    L2_MMA(0) L2_PF(0, t3 + 3)
                    L2_MMA(1) L2_PF(1, t3 + 4)
                    L2_MMA(2) L2_PF(2, t3 + 5)
                }
                L2_MMA(0) L2_MMA(1) L2_MMA(2)
                #undef acc2a
                #undef acc2b
            }
            // lane m = mbg*32+rl; reg q*4+r2 -> j = r2+8q+4hi (valid <10)
            const int m = mbg * 32 + rl;
            float mx = -1e30f;
            float lv[16];
            #pragma unroll
            for (int q = 0; q < 4; ++q)
                #pragma unroll
                for (int r2 = 0; r2 < 4; ++r2) {
                    int j = r2 + 8 * q + 4 * hi;
                    int rg = q * 4 + r2;
                    lv[rg] = (j < NEXP) ? (acc3a[rg] + acc3b[rg]) : -1e30f;
                    mx = fmaxf(mx, lv[rg]);
                }
            mx = fmaxf(mx, __shfl_xor(mx, 32, 64));
            float s = 0.f;
            float pv[16];
            #pragma unroll
            for (int rg = 0; rg < 16; ++rg) {
                pv[rg] = (lv[rg] > -1e29f) ? __expf(lv[rg] - mx) : 0.f;
                s += pv[rg];
            }
            s += __shfl_xor(s, 32, 64);
            const float inv = 1.f / s;
            #pragma unroll
            for (int q = 0; q < 4; ++q)
                #pragma unroll
                for (int r2 = 0; r2 < 4; ++r2) {
                    int j = r2 + 8 * q + 4 * hi;
                    if (j < NEXP) {
                        float g  = pv[q * 4 + r2] * inv;
                        float eo = expl2[m * (NEXP * 2) + j * 2]
                                 + expl2[m * (NEXP * 2) + j * 2 + 1]
                                 + b3s[j];
                        size_t o = (size_t)(row0 + m) * NEXP + j;
                        out[o] = g * eo;
                        out[(size_t)BTOT * NEXP + o] = g;
                        out[(size_t)2 * BTOT * NEXP + o] = eo;
                    }
                }
        }
    }
}

extern "C" void kernel_launch(void* const* d_in, const int* in_sizes, int n_in,
                              void* d_out, int out_size, void* d_ws, size_t ws_size,
                              hipStream_t stream) {
    (void)in_sizes; (void)n_in; (void)out_size; (void)ws_size;
    const float* x   = (const float*)d_in[0];
    const float* W1  = (const float*)d_in[1];
    const float* b1  = (const float*)d_in[2];
    const float* W2  = (const float*)d_in[3];
    const float* b2  = (const float*)d_in[4];
    const float* W3  = (const float*)d_in[5];
    const float* b3  = (const float*)d_in[6];
    const float* Wg1 = (const float*)d_in[7];
    const float* bg1 = (const float*)d_in[8];
    const float* Wg2 = (const float*)d_in[9];
    const float* bg2 = (const float*)d_in[10];

    // ws (bf16, fragment order): w1t 11*8*25*2*64*8 | w2t 10*2*9*2*64*8 | wg2t 9*2*64*8
    __bf16* w1t  = (__bf16*)d_ws;
    __bf16* w2t  = w1t + (size_t)11 * 8 * 25 * 2 * 64 * 8;
    __bf16* wg2t = w2t + (size_t)10 * 2 * 9 * 2 * 64 * 8;

    hipFuncSetAttribute((const void*)moe_fused,
                        hipFuncAttributeMaxDynamicSharedMemorySize, LDS_TOTAL);

    prep_w1<<<1100, 256, 0, stream>>>(W1, b1, Wg1, bg1, w1t);
    prep_w2<<<90, 256, 0, stream>>>(W2, b2, w2t);
    prep_wg2<<<5, 256, 0, stream>>>(Wg2, bg2, wg2t);
    moe_fused<<<BTOT / BM, 256, LDS_TOTAL, stream>>>(x, W3, b3, w1t, w2t, wg2t,
                                                     (float*)d_out);
}